// Round 2
// 777.959 us; speedup vs baseline: 1.4053x; 1.4053x over previous
//
#include <hip/hip_runtime.h>
#include <hip/hip_bf16.h>

#define S_ 1024
#define D_ 1024
#define H_ 16
#define DQ_ 64
#define DV_ 32

typedef __attribute__((ext_vector_type(8))) short bf16x8;
typedef __attribute__((ext_vector_type(4))) float f32x4;

static __device__ __forceinline__ float bf2f(unsigned short u) {
    union { unsigned int i; float f; } v; v.i = ((unsigned int)u) << 16; return v.f;
}
static __device__ __forceinline__ unsigned short f2bf(float f) {
    union { float f; unsigned int i; } v; v.f = f;
    unsigned int x = v.i;
    unsigned int r = x + 0x7fffu + ((x >> 16) & 1u);
    return (unsigned short)(r >> 16);
}
static __device__ __forceinline__ f32x4 mfma16(bf16x8 a, bf16x8 b, f32x4 c) {
    return __builtin_amdgcn_mfma_f32_16x16x32_bf16(a, b, c, 0, 0, 0);
}

// Direct global->LDS DMA, 16B per lane. LDS dest must be wave-uniform base;
// HW writes base + lane*16.
static __device__ __forceinline__ void gload16(const unsigned short* g, unsigned short* l) {
    __builtin_amdgcn_global_load_lds(
        (const __attribute__((address_space(1))) unsigned int*)(unsigned long long)g,
        (__attribute__((address_space(3))) unsigned int*)(unsigned int)(unsigned long long)l,
        16, 0, 0);
}

// ---------------------------------------------------------------------------
// Dtype probe: flag=1 if raw data is bf16, 0 if fp32.
// ---------------------------------------------------------------------------
__global__ void k_detect(const unsigned short* __restrict__ X, int* __restrict__ flag) {
    int tid = threadIdx.x;               // 64 threads
    unsigned short u = X[2 * tid];
    int e = (u >> 7) & 0xFF;
    bool sane = (e >= 100 && e <= 150) || ((u & 0x7FFFu) == 0);
    unsigned long long m = __ballot(sane);
    if (tid == 0) *flag = (__popcll(m) >= 40) ? 1 : 0;
}

__global__ void k_cvt(const void* __restrict__ src, unsigned short* __restrict__ dst,
                      int n, const int* __restrict__ flag) {
    int i = blockIdx.x * 256 + threadIdx.x;
    if (i >= n) return;
    int fl = *flag;
    dst[i] = fl ? ((const unsigned short*)src)[i] : f2bf(((const float*)src)[i]);
}

__global__ void k_cvt_f(const void* __restrict__ src, float* __restrict__ dst,
                        int n, const int* __restrict__ flag) {
    int i = blockIdx.x * 256 + threadIdx.x;
    if (i >= n) return;
    int fl = *flag;
    dst[i] = fl ? bf2f(((const unsigned short*)src)[i]) : ((const float*)src)[i];
}

// ---------------------------------------------------------------------------
// Weight transpose + convert: src[K][N] (fp32/bf16) -> dst[N][K] bf16.
// ---------------------------------------------------------------------------
__global__ void k_transpose(const void* __restrict__ src,
                            unsigned short* __restrict__ dst, int K, int N,
                            const int* __restrict__ flag) {
    __shared__ unsigned short t[32][33];
    int fl = *flag;
    int n0 = blockIdx.x * 32, k0 = blockIdx.y * 32;
    int tx = threadIdx.x, ty = threadIdx.y;  // blockDim (32,8)
    for (int i = ty; i < 32; i += 8) {
        size_t idx = (size_t)(k0 + i) * N + n0 + tx;
        t[i][tx] = fl ? ((const unsigned short*)src)[idx]
                      : f2bf(((const float*)src)[idx]);
    }
    __syncthreads();
    for (int i = ty; i < 32; i += 8)
        dst[(size_t)(n0 + i) * K + k0 + tx] = t[tx][i];
}

// ---------------------------------------------------------------------------
// Fused QKV projection GEMM — m97-style 128x128 LDS-staged tile.
// WT = [2560][1024] bf16 (WqT|WkT|WvT contiguous in workspace).
// 4 waves, each owns a 64x64 quadrant (4x4 fragments of 16x16), BK=32.
// ---------------------------------------------------------------------------
__global__ __launch_bounds__(256)
void k_qkv(const unsigned short* __restrict__ Xb,
           const unsigned short* __restrict__ WT,
           const float* __restrict__ bias_f,
           unsigned short* __restrict__ q_l,
           unsigned short* __restrict__ k_l,
           unsigned short* __restrict__ vT) {
    __shared__ __align__(16) unsigned short As[128 * 32];
    __shared__ __align__(16) unsigned short Bs[128 * 32];
    int tid = threadIdx.x;
    int w = tid >> 6, lane = tid & 63;
    int m = lane & 15, quad = lane >> 4;
    int row0 = blockIdx.y * 128;
    int col0 = blockIdx.x * 128;
    int wr = w >> 1, wc = w & 1;

    const unsigned short* a0 = Xb + (size_t)(row0 + (tid >> 2)) * 1024 + (tid & 3) * 8;
    const unsigned short* b0 = WT + (size_t)(col0 + (tid >> 2)) * 1024 + (tid & 3) * 8;
    unsigned short* AsW = As + w * 512;   // wave-uniform LDS dest (bytes: w*1024)
    unsigned short* BsW = Bs + w * 512;

    f32x4 acc[4][4];
#pragma unroll
    for (int i = 0; i < 4; ++i)
#pragma unroll
        for (int j = 0; j < 4; ++j) acc[i][j] = (f32x4){0.f, 0.f, 0.f, 0.f};

    for (int k0 = 0; k0 < 1024; k0 += 32) {
        gload16(a0 + k0, AsW);
        gload16(a0 + 64 * 1024 + k0, AsW + 2048);
        gload16(b0 + k0, BsW);
        gload16(b0 + 64 * 1024 + k0, BsW + 2048);
        __syncthreads();   // compiler drains vmcnt before barrier
        bf16x8 af[4], bf[4];
#pragma unroll
        for (int f = 0; f < 4; ++f) {
            af[f] = *(const bf16x8*)&As[(wr * 64 + f * 16 + m) * 32 + quad * 8];
            bf[f] = *(const bf16x8*)&Bs[(wc * 64 + f * 16 + m) * 32 + quad * 8];
        }
#pragma unroll
        for (int i = 0; i < 4; ++i)
#pragma unroll
            for (int j = 0; j < 4; ++j)
                acc[i][j] = mfma16(af[i], bf[j], acc[i][j]);
        __syncthreads();   // protect LDS from next iteration's staging
    }

    // epilogue: scatter into q_l/k_l (head-major) and vT (dv-major transposed)
#pragma unroll
    for (int fn = 0; fn < 4; ++fn) {
        int col = col0 + wc * 64 + fn * 16 + m;
        float bval = bias_f[col];
#pragma unroll
        for (int fm = 0; fm < 4; ++fm) {
#pragma unroll
            for (int j = 0; j < 4; ++j) {
                int row = row0 + wr * 64 + fm * 16 + quad * 4 + j;
                int bb = row >> 10, ss = row & 1023;
                unsigned short o = f2bf(acc[fm][fn][j] + bval);
                if (col < 1024) {
                    int h = col >> 6, d = col & 63;
                    q_l[(((size_t)(bb * H_ + h)) * S_ + ss) * DQ_ + d] = o;
                } else if (col < 2048) {
                    int c = col - 1024; int h = c >> 6, d = c & 63;
                    k_l[(((size_t)(bb * H_ + h)) * S_ + ss) * DQ_ + d] = o;
                } else {
                    int c = col - 2048; int h = c >> 5, dv = c & 31;
                    vT[(((size_t)(bb * H_ + h)) * DV_ + dv) * S_ + ss] = o;
                }
            }
        }
    }
}

// ---------------------------------------------------------------------------
// Attention: block = one (b,h) x 16 q-rows; 4 waves split the 1024-wide k dim.
// Scores once into registers; single-exp softmax (diagonal corrected by
// corr = exp(gmF-gmB)); unnormalized e -> LDS P for probs write + PV MFMA.
// ---------------------------------------------------------------------------
__global__ __launch_bounds__(256)
void k_attn(const unsigned short* __restrict__ q_l,
            const unsigned short* __restrict__ k_l,
            const unsigned short* __restrict__ vT,
            unsigned short* __restrict__ probs_b,  // bf16 view (flag=1)
            float* __restrict__ probs_f,           // fp32 view (flag=0)
            unsigned short* __restrict__ Y,        // [b][s][1024] bf16
            const int* __restrict__ flag) {
    __shared__ __align__(16) unsigned short P[2][16][1032];  // [dir][qrow][col]
    __shared__ float redM[4][2][16];
    __shared__ float redL[4][2][16];
    int fl = *flag;
    int tid = threadIdx.x;
    int w = tid >> 6, lane = tid & 63;
    int m = lane & 15, quad = lane >> 4;
    int bh = blockIdx.x;
    int q0 = blockIdx.y * 16;
    int kbase = w * 256;

    const unsigned short* qp = q_l + (size_t)bh * S_ * DQ_;
    const unsigned short* kp = k_l + (size_t)bh * S_ * DQ_;
    const unsigned short* vp = vT  + (size_t)bh * DV_ * S_;

    bf16x8 qa0 = *(const bf16x8*)(qp + (size_t)(q0 + m) * DQ_ + quad * 8);
    bf16x8 qa1 = *(const bf16x8*)(qp + (size_t)(q0 + m) * DQ_ + 32 + quad * 8);

    // ---- scores once, into registers: sc[t][j], col = kbase+t*16+m, row = q0+quad*4+j
    float sc[16][4];
#pragma unroll
    for (int t = 0; t < 16; ++t) {
        const unsigned short* krow = kp + (size_t)((kbase >> 4) * 16 + t * 16 + m) * DQ_;
        bf16x8 kb0 = *(const bf16x8*)(krow + quad * 8);
        bf16x8 kb1 = *(const bf16x8*)(krow + 32 + quad * 8);
        f32x4 s = {0.f, 0.f, 0.f, 0.f};
        s = mfma16(qa0, kb0, s);
        s = mfma16(qa1, kb1, s);
#pragma unroll
        for (int j = 0; j < 4; ++j) sc[t][j] = s[j] * 0.125f;
    }

    // ---- per-row masked max: registers -> quad shfl -> LDS
#pragma unroll
    for (int j = 0; j < 4; ++j) {
        int row = quad * 4 + j;
        int r = q0 + row;
        float mF = -3e38f, mB = -3e38f;
#pragma unroll
        for (int t = 0; t < 16; ++t) {
            int c = kbase + t * 16 + m;
            float v = sc[t][j];
            mF = (c <= r) ? fmaxf(mF, v) : mF;
            mB = (c >= r) ? fmaxf(mB, v) : mB;
        }
        mF = fmaxf(mF, __shfl_xor(mF, 1, 64));
        mF = fmaxf(mF, __shfl_xor(mF, 2, 64));
        mF = fmaxf(mF, __shfl_xor(mF, 4, 64));
        mF = fmaxf(mF, __shfl_xor(mF, 8, 64));
        mB = fmaxf(mB, __shfl_xor(mB, 1, 64));
        mB = fmaxf(mB, __shfl_xor(mB, 2, 64));
        mB = fmaxf(mB, __shfl_xor(mB, 4, 64));
        mB = fmaxf(mB, __shfl_xor(mB, 8, 64));
        if (m == 0) { redM[w][0][row] = mF; redM[w][1][row] = mB; }
    }
    __syncthreads();

    // ---- single-exp: e = exp(s - dir-max); diagonal bwd fixed by corr
#pragma unroll
    for (int j = 0; j < 4; ++j) {
        int row = quad * 4 + j;
        int r = q0 + row;
        float gmF = fmaxf(fmaxf(redM[0][0][row], redM[1][0][row]),
                          fmaxf(redM[2][0][row], redM[3][0][row]));
        float gmB = fmaxf(fmaxf(redM[0][1][row], redM[1][1][row]),
                          fmaxf(redM[2][1][row], redM[3][1][row]));
        float corr = __expf(gmF - gmB);  // exp(v-gmB) = exp(v-gmF)*corr at diagonal
        float sF = 0.f, sB = 0.f;
#pragma unroll
        for (int t = 0; t < 16; ++t) {
            int c = kbase + t * 16 + m;
            float v = sc[t][j];
            bool fwd = (c <= r);
            float e = __expf(v - (fwd ? gmF : gmB));
            float eF = fwd ? e : 0.f;
            float eB = (c > r) ? e : ((c == r) ? e * corr : 0.f);
            sF += eF; sB += eB;
            P[0][row][c] = f2bf(eF);
            P[1][row][c] = f2bf(eB);
        }
        sF += __shfl_xor(sF, 1, 64);
        sF += __shfl_xor(sF, 2, 64);
        sF += __shfl_xor(sF, 4, 64);
        sF += __shfl_xor(sF, 8, 64);
        sB += __shfl_xor(sB, 1, 64);
        sB += __shfl_xor(sB, 2, 64);
        sB += __shfl_xor(sB, 4, 64);
        sB += __shfl_xor(sB, 8, 64);
        if (m == 0) { redL[w][0][row] = sF; redL[w][1][row] = sB; }
    }
    __syncthreads();

    // ---- coalesced probs write: 256 threads x 32 iters x float4
    size_t pbase = (size_t)bh << 21;  // bh * 1024 * 2048
#pragma unroll 4
    for (int i = 0; i < 32; ++i) {
        int row = i >> 1, dir = i & 1;
        int col4 = tid * 4;
        ushort4 ev = *(const ushort4*)&P[dir][row][col4];
        float l = redL[0][dir][row] + redL[1][dir][row] +
                  redL[2][dir][row] + redL[3][dir][row];
        float inv = 1.f / l;
        size_t off = pbase + (size_t)(q0 + row) * 2048 + (size_t)dir * 1024 + col4;
        if (fl) {
            ushort4 o;
            o.x = f2bf(bf2f(ev.x) * inv); o.y = f2bf(bf2f(ev.y) * inv);
            o.z = f2bf(bf2f(ev.z) * inv); o.w = f2bf(bf2f(ev.w) * inv);
            *(ushort4*)(probs_b + off) = o;
        } else {
            float4 o = { bf2f(ev.x) * inv, bf2f(ev.y) * inv,
                         bf2f(ev.z) * inv, bf2f(ev.w) * inv };
            *(float4*)(probs_f + off) = o;
        }
    }

    // ---- PV: wave = dir x dv-half; C[16 q x 16 dv], k over full 1024
    {
        int dir = w >> 1, half = w & 1;
        const unsigned short* vrow = vp + (size_t)(half * 16 + m) * S_;
        f32x4 acc0 = {0.f,0.f,0.f,0.f}, acc1 = {0.f,0.f,0.f,0.f};
#pragma unroll
        for (int it = 0; it < 32; it += 2) {
            bf16x8 a0 = *(const bf16x8*)&P[dir][m][it * 32 + quad * 8];
            bf16x8 b0 = *(const bf16x8*)(vrow + it * 32 + quad * 8);
            acc0 = mfma16(a0, b0, acc0);
            bf16x8 a1 = *(const bf16x8*)&P[dir][m][it * 32 + 32 + quad * 8];
            bf16x8 b1 = *(const bf16x8*)(vrow + it * 32 + 32 + quad * 8);
            acc1 = mfma16(a1, b1, acc1);
        }
        int b_ = bh >> 4, h_ = bh & 15;
#pragma unroll
        for (int j = 0; j < 4; ++j) {
            int row = quad * 4 + j;
            float l = redL[0][dir][row] + redL[1][dir][row] +
                      redL[2][dir][row] + redL[3][dir][row];
            float v = (acc0[j] + acc1[j]) / l;
            Y[((size_t)(b_ * 1024 + q0 + row)) * 1024 +
              dir * 512 + h_ * 32 + half * 16 + m] = f2bf(v);
        }
    }
}

// ---------------------------------------------------------------------------
// Output projection — same m97-style 128x128 LDS-staged tile.
// ---------------------------------------------------------------------------
__global__ __launch_bounds__(256)
void k_out(const unsigned short* __restrict__ Y,
           const unsigned short* __restrict__ WoT,
           const float* __restrict__ bo,
           unsigned short* __restrict__ out_b,
           float* __restrict__ out_f,
           const int* __restrict__ flag) {
    __shared__ __align__(16) unsigned short As[128 * 32];
    __shared__ __align__(16) unsigned short Bs[128 * 32];
    int fl = *flag;
    int tid = threadIdx.x;
    int w = tid >> 6, lane = tid & 63;
    int m = lane & 15, quad = lane >> 4;
    int row0 = blockIdx.y * 128;
    int col0 = blockIdx.x * 128;
    int wr = w >> 1, wc = w & 1;

    const unsigned short* a0 = Y   + (size_t)(row0 + (tid >> 2)) * 1024 + (tid & 3) * 8;
    const unsigned short* b0 = WoT + (size_t)(col0 + (tid >> 2)) * 1024 + (tid & 3) * 8;
    unsigned short* AsW = As + w * 512;
    unsigned short* BsW = Bs + w * 512;

    f32x4 acc[4][4];
#pragma unroll
    for (int i = 0; i < 4; ++i)
#pragma unroll
        for (int j = 0; j < 4; ++j) acc[i][j] = (f32x4){0.f, 0.f, 0.f, 0.f};

    for (int k0 = 0; k0 < 1024; k0 += 32) {
        gload16(a0 + k0, AsW);
        gload16(a0 + 64 * 1024 + k0, AsW + 2048);
        gload16(b0 + k0, BsW);
        gload16(b0 + 64 * 1024 + k0, BsW + 2048);
        __syncthreads();
        bf16x8 af[4], bf[4];
#pragma unroll
        for (int f = 0; f < 4; ++f) {
            af[f] = *(const bf16x8*)&As[(wr * 64 + f * 16 + m) * 32 + quad * 8];
            bf[f] = *(const bf16x8*)&Bs[(wc * 64 + f * 16 + m) * 32 + quad * 8];
        }
#pragma unroll
        for (int i = 0; i < 4; ++i)
#pragma unroll
            for (int j = 0; j < 4; ++j)
                acc[i][j] = mfma16(af[i], bf[j], acc[i][j]);
        __syncthreads();
    }

#pragma unroll
    for (int fn = 0; fn < 4; ++fn) {
        int col = col0 + wc * 64 + fn * 16 + m;
        float bval = bo[col];
#pragma unroll
        for (int fm = 0; fm < 4; ++fm) {
#pragma unroll
            for (int j = 0; j < 4; ++j) {
                int row = row0 + wr * 64 + fm * 16 + quad * 4 + j;
                float v = acc[fm][fn][j] + bval;
                if (fl) out_b[(size_t)row * 1024 + col] = f2bf(v);
                else    out_f[(size_t)row * 1024 + col] = v;
            }
        }
    }
}

// ---------------------------------------------------------------------------
extern "C" void kernel_launch(void* const* d_in, const int* in_sizes, int n_in,
                              void* d_out, int out_size, void* d_ws, size_t ws_size,
                              hipStream_t stream) {
    const void* X  = d_in[0];
    const void* Wq = d_in[1];
    const void* bq = d_in[2];
    const void* Wk = d_in[3];
    const void* bk = d_in[4];
    const void* Wv = d_in[5];
    const void* bv = d_in[6];
    const void* Wo = d_in[7];
    const void* bo = d_in[8];

    unsigned short* ws  = (unsigned short*)d_ws;
    unsigned short* Xb  = ws;               //  4,194,304 bf16
    unsigned short* q_l = ws + 4194304;     //  4,194,304
    unsigned short* k_l = ws + 8388608;     //  4,194,304
    unsigned short* vT  = ws + 12582912;    //  2,097,152
    unsigned short* Y   = ws + 14680064;    //  4,194,304
    unsigned short* WqT = ws + 18874368;    //  1,048,576 (WqT|WkT|WvT contiguous)
    unsigned short* WkT = ws + 19922944;    //  1,048,576
    unsigned short* WvT = ws + 20971520;    //    524,288
    unsigned short* WoT = ws + 21495808;    //  1,048,576
    float*  bias_f = (float*)(ws + 22544384);  // 3584 floats
    int*    flag   = (int*)(bias_f + 3584);

    k_detect<<<1, 64, 0, stream>>>((const unsigned short*)X, flag);

    dim3 tb(32, 8);
    k_transpose<<<dim3(32, 32), tb, 0, stream>>>(Wq, WqT, 1024, 1024, flag);
    k_transpose<<<dim3(32, 32), tb, 0, stream>>>(Wk, WkT, 1024, 1024, flag);
    k_transpose<<<dim3(16, 32), tb, 0, stream>>>(Wv, WvT, 1024, 512, flag);
    k_transpose<<<dim3(32, 32), tb, 0, stream>>>(Wo, WoT, 1024, 1024, flag);

    k_cvt<<<16384, 256, 0, stream>>>(X, Xb, 4194304, flag);
    k_cvt_f<<<4, 256, 0, stream>>>(bq, bias_f,        1024, flag);
    k_cvt_f<<<4, 256, 0, stream>>>(bk, bias_f + 1024, 1024, flag);
    k_cvt_f<<<2, 256, 0, stream>>>(bv, bias_f + 2048,  512, flag);
    k_cvt_f<<<4, 256, 0, stream>>>(bo, bias_f + 2560, 1024, flag);

    // 128x128 tiles: N=2560 -> 20 col tiles (each tile lies within one of Wq/Wk/Wv)
    k_qkv<<<dim3(20, 32), 256, 0, stream>>>(Xb, WqT, bias_f, q_l, k_l, vT);
    k_attn<<<dim3(64, 64), 256, 0, stream>>>(q_l, k_l, vT,
                                             (unsigned short*)d_out + 4194304,
                                             (float*)d_out + 4194304, Y, flag);
    k_out<<<dim3(8, 32), 256, 0, stream>>>(Y, WoT, bias_f + 2560,
                                           (unsigned short*)d_out, (float*)d_out, flag);
}

// Round 3
// 752.142 us; speedup vs baseline: 1.4535x; 1.0343x over previous
//
#include <hip/hip_runtime.h>
#include <hip/hip_bf16.h>

#define S_ 1024
#define D_ 1024
#define H_ 16
#define DQ_ 64
#define DV_ 32

typedef __attribute__((ext_vector_type(8))) short bf16x8;
typedef __attribute__((ext_vector_type(4))) float f32x4;

static __device__ __forceinline__ float bf2f(unsigned short u) {
    union { unsigned int i; float f; } v; v.i = ((unsigned int)u) << 16; return v.f;
}
static __device__ __forceinline__ unsigned short f2bf(float f) {
    union { float f; unsigned int i; } v; v.f = f;
    unsigned int x = v.i;
    unsigned int r = x + 0x7fffu + ((x >> 16) & 1u);
    return (unsigned short)(r >> 16);
}
static __device__ __forceinline__ f32x4 mfma16(bf16x8 a, bf16x8 b, f32x4 c) {
    return __builtin_amdgcn_mfma_f32_16x16x32_bf16(a, b, c, 0, 0, 0);
}

// Direct global->LDS DMA, 16B per lane. LDS dest must be wave-uniform base;
// HW writes base + lane*16.
static __device__ __forceinline__ void gload16(const unsigned short* g, unsigned short* l) {
    __builtin_amdgcn_global_load_lds(
        (const __attribute__((address_space(1))) unsigned int*)(unsigned long long)g,
        (__attribute__((address_space(3))) unsigned int*)(unsigned int)(unsigned long long)l,
        16, 0, 0);
}

// ---------------------------------------------------------------------------
// Dtype probe: flag=1 if raw data is bf16, 0 if fp32.
// ---------------------------------------------------------------------------
__global__ void k_detect(const unsigned short* __restrict__ X, int* __restrict__ flag) {
    int tid = threadIdx.x;               // 64 threads
    unsigned short u = X[2 * tid];
    int e = (u >> 7) & 0xFF;
    bool sane = (e >= 100 && e <= 150) || ((u & 0x7FFFu) == 0);
    unsigned long long m = __ballot(sane);
    if (tid == 0) *flag = (__popcll(m) >= 40) ? 1 : 0;
}

__global__ void k_cvt(const void* __restrict__ src, unsigned short* __restrict__ dst,
                      int n, const int* __restrict__ flag) {
    int i = blockIdx.x * 256 + threadIdx.x;
    if (i >= n) return;
    int fl = *flag;
    dst[i] = fl ? ((const unsigned short*)src)[i] : f2bf(((const float*)src)[i]);
}

// All four bias vectors in one launch: dst layout [bq|bk|bv|bo] = 3584 floats.
__global__ void k_bias(const void* __restrict__ bq, const void* __restrict__ bk,
                       const void* __restrict__ bv, const void* __restrict__ bo,
                       float* __restrict__ dst, const int* __restrict__ flag) {
    int i = blockIdx.x * 256 + threadIdx.x;
    if (i >= 3584) return;
    int fl = *flag;
    const void* src; int off;
    if (i < 1024)      { src = bq; off = i; }
    else if (i < 2048) { src = bk; off = i - 1024; }
    else if (i < 2560) { src = bv; off = i - 2048; }
    else               { src = bo; off = i - 2560; }
    dst[i] = fl ? bf2f(((const unsigned short*)src)[off]) : ((const float*)src)[off];
}

// ---------------------------------------------------------------------------
// All four weight transposes in one launch (z selects matrix).
// src[K=1024][N] (fp32/bf16) -> dst[N][1024] bf16.
// ---------------------------------------------------------------------------
__global__ void k_transpose4(const void* __restrict__ Wq, const void* __restrict__ Wk,
                             const void* __restrict__ Wv, const void* __restrict__ Wo,
                             unsigned short* __restrict__ WqT, unsigned short* __restrict__ WkT,
                             unsigned short* __restrict__ WvT, unsigned short* __restrict__ WoT,
                             const int* __restrict__ flag) {
    __shared__ unsigned short t[32][33];
    int z = blockIdx.z;
    const void* src; unsigned short* dst; int N;
    if (z == 0)      { src = Wq; dst = WqT; N = 1024; }
    else if (z == 1) { src = Wk; dst = WkT; N = 1024; }
    else if (z == 2) { src = Wv; dst = WvT; N = 512; }
    else             { src = Wo; dst = WoT; N = 1024; }
    int n0 = blockIdx.x * 32, k0 = blockIdx.y * 32;
    if (n0 >= N) return;  // uniform per block (Wv has only 16 x-tiles)
    int fl = *flag;
    int tx = threadIdx.x, ty = threadIdx.y;  // blockDim (32,8)
    for (int i = ty; i < 32; i += 8) {
        size_t idx = (size_t)(k0 + i) * N + n0 + tx;
        t[i][tx] = fl ? ((const unsigned short*)src)[idx]
                      : f2bf(((const float*)src)[idx]);
    }
    __syncthreads();
    for (int i = ty; i < 32; i += 8)
        dst[(size_t)(n0 + i) * 1024 + k0 + tx] = t[tx][i];
}

// ---------------------------------------------------------------------------
// Fused QKV projection GEMM — 128x128 LDS-staged tile, BK=32, 4 waves.
// WT = [2560][1024] bf16 (WqT|WkT|WvT contiguous in workspace).
// ---------------------------------------------------------------------------
__global__ __launch_bounds__(256)
void k_qkv(const unsigned short* __restrict__ Xb,
           const unsigned short* __restrict__ WT,
           const float* __restrict__ bias_f,
           unsigned short* __restrict__ q_l,
           unsigned short* __restrict__ k_l,
           unsigned short* __restrict__ vT) {
    __shared__ __align__(16) unsigned short As[128 * 32];
    __shared__ __align__(16) unsigned short Bs[128 * 32];
    int tid = threadIdx.x;
    int w = tid >> 6, lane = tid & 63;
    int m = lane & 15, quad = lane >> 4;
    int row0 = blockIdx.y * 128;
    int col0 = blockIdx.x * 128;
    int wr = w >> 1, wc = w & 1;

    const unsigned short* a0 = Xb + (size_t)(row0 + (tid >> 2)) * 1024 + (tid & 3) * 8;
    const unsigned short* b0 = WT + (size_t)(col0 + (tid >> 2)) * 1024 + (tid & 3) * 8;
    unsigned short* AsW = As + w * 512;   // wave-uniform LDS dest (bytes: w*1024)
    unsigned short* BsW = Bs + w * 512;

    f32x4 acc[4][4];
#pragma unroll
    for (int i = 0; i < 4; ++i)
#pragma unroll
        for (int j = 0; j < 4; ++j) acc[i][j] = (f32x4){0.f, 0.f, 0.f, 0.f};

    for (int k0 = 0; k0 < 1024; k0 += 32) {
        gload16(a0 + k0, AsW);
        gload16(a0 + 64 * 1024 + k0, AsW + 2048);
        gload16(b0 + k0, BsW);
        gload16(b0 + 64 * 1024 + k0, BsW + 2048);
        __syncthreads();
        bf16x8 af[4], bfr[4];
#pragma unroll
        for (int f = 0; f < 4; ++f) {
            af[f]  = *(const bf16x8*)&As[(wr * 64 + f * 16 + m) * 32 + quad * 8];
            bfr[f] = *(const bf16x8*)&Bs[(wc * 64 + f * 16 + m) * 32 + quad * 8];
        }
#pragma unroll
        for (int i = 0; i < 4; ++i)
#pragma unroll
            for (int j = 0; j < 4; ++j)
                acc[i][j] = mfma16(af[i], bfr[j], acc[i][j]);
        __syncthreads();
    }

    // epilogue: scatter into q_l/k_l (head-major) and vT (dv-major transposed)
#pragma unroll
    for (int fn = 0; fn < 4; ++fn) {
        int col = col0 + wc * 64 + fn * 16 + m;
        float bval = bias_f[col];
#pragma unroll
        for (int fm = 0; fm < 4; ++fm) {
#pragma unroll
            for (int j = 0; j < 4; ++j) {
                int row = row0 + wr * 64 + fm * 16 + quad * 4 + j;
                int bb = row >> 10, ss = row & 1023;
                unsigned short o = f2bf(acc[fm][fn][j] + bval);
                if (col < 1024) {
                    int h = col >> 6, d = col & 63;
                    q_l[(((size_t)(bb * H_ + h)) * S_ + ss) * DQ_ + d] = o;
                } else if (col < 2048) {
                    int c = col - 1024; int h = c >> 6, d = c & 63;
                    k_l[(((size_t)(bb * H_ + h)) * S_ + ss) * DQ_ + d] = o;
                } else {
                    int c = col - 2048; int h = c >> 5, dv = c & 31;
                    vT[(((size_t)(bb * H_ + h)) * DV_ + dv) * S_ + ss] = o;
                }
            }
        }
    }
}

// ---------------------------------------------------------------------------
// Attention: block = one (b,h) x 16 q-rows; 4 waves split the 1024-wide k dim.
// Max fused into score loop; single-exp softmax (diagonal corrected by corr);
// v_rcp for normalizers; unnormalized e -> LDS P for probs write + PV MFMA.
// ---------------------------------------------------------------------------
__global__ __launch_bounds__(256)
void k_attn(const unsigned short* __restrict__ q_l,
            const unsigned short* __restrict__ k_l,
            const unsigned short* __restrict__ vT,
            unsigned short* __restrict__ probs_b,  // bf16 view (flag=1)
            float* __restrict__ probs_f,           // fp32 view (flag=0)
            unsigned short* __restrict__ Y,        // [b][s][1024] bf16
            const int* __restrict__ flag) {
    __shared__ __align__(16) unsigned short P[2][16][1032];  // [dir][qrow][col]
    __shared__ float redM[4][2][16];
    __shared__ float redL[4][2][16];
    int fl = *flag;
    int tid = threadIdx.x;
    int w = tid >> 6, lane = tid & 63;
    int m = lane & 15, quad = lane >> 4;
    int bh = blockIdx.x;
    int q0 = blockIdx.y * 16;
    int kbase = w * 256;

    const unsigned short* qp = q_l + (size_t)bh * S_ * DQ_;
    const unsigned short* kp = k_l + (size_t)bh * S_ * DQ_;
    const unsigned short* vp = vT  + (size_t)bh * DV_ * S_;

    bf16x8 qa0 = *(const bf16x8*)(qp + (size_t)(q0 + m) * DQ_ + quad * 8);
    bf16x8 qa1 = *(const bf16x8*)(qp + (size_t)(q0 + m) * DQ_ + 32 + quad * 8);

    // ---- scores once, max fused: sc[t][j], col = kbase+t*16+m, row = q0+quad*4+j
    float sc[16][4];
    float mF[4] = {-3e38f, -3e38f, -3e38f, -3e38f};
    float mB[4] = {-3e38f, -3e38f, -3e38f, -3e38f};
#pragma unroll
    for (int t = 0; t < 16; ++t) {
        const unsigned short* krow = kp + (size_t)(kbase + t * 16 + m) * DQ_;
        bf16x8 kb0 = *(const bf16x8*)(krow + quad * 8);
        bf16x8 kb1 = *(const bf16x8*)(krow + 32 + quad * 8);
        f32x4 s = {0.f, 0.f, 0.f, 0.f};
        s = mfma16(qa0, kb0, s);
        s = mfma16(qa1, kb1, s);
        int c = kbase + t * 16 + m;
#pragma unroll
        for (int j = 0; j < 4; ++j) {
            float v = s[j] * 0.125f;
            sc[t][j] = v;
            int r = q0 + quad * 4 + j;
            if (c <= r) mF[j] = fmaxf(mF[j], v);
            if (c >= r) mB[j] = fmaxf(mB[j], v);
        }
    }

    // ---- cross-lane max reduce -> LDS
#pragma unroll
    for (int j = 0; j < 4; ++j) {
        int row = quad * 4 + j;
        float f = mF[j], b = mB[j];
        f = fmaxf(f, __shfl_xor(f, 1, 64));
        f = fmaxf(f, __shfl_xor(f, 2, 64));
        f = fmaxf(f, __shfl_xor(f, 4, 64));
        f = fmaxf(f, __shfl_xor(f, 8, 64));
        b = fmaxf(b, __shfl_xor(b, 1, 64));
        b = fmaxf(b, __shfl_xor(b, 2, 64));
        b = fmaxf(b, __shfl_xor(b, 4, 64));
        b = fmaxf(b, __shfl_xor(b, 8, 64));
        if (m == 0) { redM[w][0][row] = f; redM[w][1][row] = b; }
    }
    __syncthreads();

    // ---- single-exp: e = exp(s - dir-max); diagonal bwd fixed by corr
#pragma unroll
    for (int j = 0; j < 4; ++j) {
        int row = quad * 4 + j;
        int r = q0 + row;
        float gmF = fmaxf(fmaxf(redM[0][0][row], redM[1][0][row]),
                          fmaxf(redM[2][0][row], redM[3][0][row]));
        float gmB = fmaxf(fmaxf(redM[0][1][row], redM[1][1][row]),
                          fmaxf(redM[2][1][row], redM[3][1][row]));
        float corr = __expf(gmF - gmB);  // exp(v-gmB) = exp(v-gmF)*corr at diagonal
        float sF = 0.f, sB = 0.f;
#pragma unroll
        for (int t = 0; t < 16; ++t) {
            int c = kbase + t * 16 + m;
            float v = sc[t][j];
            bool fwd = (c <= r);
            float e = __expf(v - (fwd ? gmF : gmB));
            float eF = fwd ? e : 0.f;
            float eB = (c > r) ? e : ((c == r) ? e * corr : 0.f);
            sF += eF; sB += eB;
            P[0][row][c] = f2bf(eF);
            P[1][row][c] = f2bf(eB);
        }
        sF += __shfl_xor(sF, 1, 64);
        sF += __shfl_xor(sF, 2, 64);
        sF += __shfl_xor(sF, 4, 64);
        sF += __shfl_xor(sF, 8, 64);
        sB += __shfl_xor(sB, 1, 64);
        sB += __shfl_xor(sB, 2, 64);
        sB += __shfl_xor(sB, 4, 64);
        sB += __shfl_xor(sB, 8, 64);
        if (m == 0) { redL[w][0][row] = sF; redL[w][1][row] = sB; }
    }
    __syncthreads();

    // ---- coalesced probs write: 256 threads x 32 iters x 16B/8B
    size_t pbase = (size_t)bh << 21;  // bh * 1024 * 2048
#pragma unroll 4
    for (int i = 0; i < 32; ++i) {
        int row = i >> 1, dir = i & 1;
        int col4 = tid * 4;
        ushort4 ev = *(const ushort4*)&P[dir][row][col4];
        float l = redL[0][dir][row] + redL[1][dir][row] +
                  redL[2][dir][row] + redL[3][dir][row];
        float inv = __builtin_amdgcn_rcpf(l);
        size_t off = pbase + (size_t)(q0 + row) * 2048 + (size_t)dir * 1024 + col4;
        if (fl) {
            ushort4 o;
            o.x = f2bf(bf2f(ev.x) * inv); o.y = f2bf(bf2f(ev.y) * inv);
            o.z = f2bf(bf2f(ev.z) * inv); o.w = f2bf(bf2f(ev.w) * inv);
            *(ushort4*)(probs_b + off) = o;
        } else {
            float4 o = { bf2f(ev.x) * inv, bf2f(ev.y) * inv,
                         bf2f(ev.z) * inv, bf2f(ev.w) * inv };
            *(float4*)(probs_f + off) = o;
        }
    }

    // ---- PV: wave = dir x dv-half; C[16 q x 16 dv], k over full 1024
    {
        int dir = w >> 1, half = w & 1;
        const unsigned short* vrow = vp + (size_t)(half * 16 + m) * S_;
        f32x4 acc0 = {0.f,0.f,0.f,0.f}, acc1 = {0.f,0.f,0.f,0.f};
#pragma unroll
        for (int it = 0; it < 32; it += 2) {
            bf16x8 a0 = *(const bf16x8*)&P[dir][m][it * 32 + quad * 8];
            bf16x8 b0 = *(const bf16x8*)(vrow + it * 32 + quad * 8);
            acc0 = mfma16(a0, b0, acc0);
            bf16x8 a1 = *(const bf16x8*)&P[dir][m][it * 32 + 32 + quad * 8];
            bf16x8 b1 = *(const bf16x8*)(vrow + it * 32 + 32 + quad * 8);
            acc1 = mfma16(a1, b1, acc1);
        }
        int b_ = bh >> 4, h_ = bh & 15;
#pragma unroll
        for (int j = 0; j < 4; ++j) {
            int row = quad * 4 + j;
            float l = redL[0][dir][row] + redL[1][dir][row] +
                      redL[2][dir][row] + redL[3][dir][row];
            float v = (acc0[j] + acc1[j]) * __builtin_amdgcn_rcpf(l);
            Y[((size_t)(b_ * 1024 + q0 + row)) * 1024 +
              dir * 512 + h_ * 32 + half * 16 + m] = f2bf(v);
        }
    }
}

// ---------------------------------------------------------------------------
// Output projection — 128x64 tile, grid 512 blocks = 2/CU so barrier drains
// overlap across blocks (previous 128x128 grid was 256 = 1/CU, no overlap).
// ---------------------------------------------------------------------------
__global__ __launch_bounds__(256)
void k_out(const unsigned short* __restrict__ Y,
           const unsigned short* __restrict__ WoT,
           const float* __restrict__ bo,
           unsigned short* __restrict__ out_b,
           float* __restrict__ out_f,
           const int* __restrict__ flag) {
    __shared__ __align__(16) unsigned short As[128 * 32];
    __shared__ __align__(16) unsigned short Bs[64 * 32];
    int fl = *flag;
    int tid = threadIdx.x;
    int w = tid >> 6, lane = tid & 63;
    int m = lane & 15, quad = lane >> 4;
    int row0 = blockIdx.y * 128;
    int col0 = blockIdx.x * 64;
    int wr = w >> 1, wc = w & 1;   // wave quadrant: 64 rows x 32 cols

    const unsigned short* a0 = Y   + (size_t)(row0 + (tid >> 2)) * 1024 + (tid & 3) * 8;
    const unsigned short* b0 = WoT + (size_t)(col0 + (tid >> 2)) * 1024 + (tid & 3) * 8;
    unsigned short* AsW = As + w * 512;
    unsigned short* BsW = Bs + w * 512;   // 4 waves cover all 64x32

    f32x4 acc[4][2];
#pragma unroll
    for (int i = 0; i < 4; ++i)
#pragma unroll
        for (int j = 0; j < 2; ++j) acc[i][j] = (f32x4){0.f, 0.f, 0.f, 0.f};

    for (int k0 = 0; k0 < 1024; k0 += 32) {
        gload16(a0 + k0, AsW);
        gload16(a0 + 64 * 1024 + k0, AsW + 2048);
        gload16(b0 + k0, BsW);
        __syncthreads();
        bf16x8 af[4], bfr[2];
#pragma unroll
        for (int f = 0; f < 4; ++f)
            af[f] = *(const bf16x8*)&As[(wr * 64 + f * 16 + m) * 32 + quad * 8];
#pragma unroll
        for (int f = 0; f < 2; ++f)
            bfr[f] = *(const bf16x8*)&Bs[(wc * 32 + f * 16 + m) * 32 + quad * 8];
#pragma unroll
        for (int i = 0; i < 4; ++i)
#pragma unroll
            for (int j = 0; j < 2; ++j)
                acc[i][j] = mfma16(af[i], bfr[j], acc[i][j]);
        __syncthreads();
    }

#pragma unroll
    for (int fn = 0; fn < 2; ++fn) {
        int col = col0 + wc * 32 + fn * 16 + m;
        float bval = bo[col];
#pragma unroll
        for (int fm = 0; fm < 4; ++fm) {
#pragma unroll
            for (int j = 0; j < 4; ++j) {
                int row = row0 + wr * 64 + fm * 16 + quad * 4 + j;
                float v = acc[fm][fn][j] + bval;
                if (fl) out_b[(size_t)row * 1024 + col] = f2bf(v);
                else    out_f[(size_t)row * 1024 + col] = v;
            }
        }
    }
}

// ---------------------------------------------------------------------------
extern "C" void kernel_launch(void* const* d_in, const int* in_sizes, int n_in,
                              void* d_out, int out_size, void* d_ws, size_t ws_size,
                              hipStream_t stream) {
    const void* X  = d_in[0];
    const void* Wq = d_in[1];
    const void* bq = d_in[2];
    const void* Wk = d_in[3];
    const void* bk = d_in[4];
    const void* Wv = d_in[5];
    const void* bv = d_in[6];
    const void* Wo = d_in[7];
    const void* bo = d_in[8];

    unsigned short* ws  = (unsigned short*)d_ws;
    unsigned short* Xb  = ws;               //  4,194,304 bf16
    unsigned short* q_l = ws + 4194304;     //  4,194,304
    unsigned short* k_l = ws + 8388608;     //  4,194,304
    unsigned short* vT  = ws + 12582912;    //  2,097,152
    unsigned short* Y   = ws + 14680064;    //  4,194,304
    unsigned short* WqT = ws + 18874368;    //  1,048,576 (WqT|WkT|WvT contiguous)
    unsigned short* WkT = ws + 19922944;    //  1,048,576
    unsigned short* WvT = ws + 20971520;    //    524,288
    unsigned short* WoT = ws + 21495808;    //  1,048,576
    float*  bias_f = (float*)(ws + 22544384);  // 3584 floats
    int*    flag   = (int*)(bias_f + 3584);

    k_detect<<<1, 64, 0, stream>>>((const unsigned short*)X, flag);

    k_transpose4<<<dim3(32, 32, 4), dim3(32, 8), 0, stream>>>(
        Wq, Wk, Wv, Wo, WqT, WkT, WvT, WoT, flag);

    k_cvt<<<16384, 256, 0, stream>>>(X, Xb, 4194304, flag);
    k_bias<<<14, 256, 0, stream>>>(bq, bk, bv, bo, bias_f, flag);

    // 128x128 tiles: N=2560 -> 20 col tiles (each tile lies within one of Wq/Wk/Wv)
    k_qkv<<<dim3(20, 32), 256, 0, stream>>>(Xb, WqT, bias_f, q_l, k_l, vT);
    k_attn<<<dim3(64, 64), 256, 0, stream>>>(q_l, k_l, vT,
                                             (unsigned short*)d_out + 4194304,
                                             (float*)d_out + 4194304, Y, flag);
    k_out<<<dim3(16, 32), 256, 0, stream>>>(Y, WoT, bias_f + 2560,
                                            (unsigned short*)d_out, (float*)d_out, flag);
}